// Round 1
// baseline (12155.234 us; speedup 1.0000x reference)
//
#include <hip/hip_runtime.h>
#include <hip/hip_bf16.h>

#define HIDDEN 128
#define NRBF 64

// ---------------------------------------------------------------------------
// w1t[f][r] = w1[r][f]  (64x128 -> 128x64) so the edge kernel reads w1 rows
// contiguously with uniform (scalar) addresses.
// ---------------------------------------------------------------------------
__global__ void transpose_w1(const float* __restrict__ w1, float* __restrict__ w1t) {
    int idx = blockIdx.x * 256 + threadIdx.x;
    if (idx < NRBF * HIDDEN) {
        int r = idx >> 7;        // 0..63
        int f = idx & 127;       // 0..127
        w1t[f * NRBF + r] = w1[idx];
    }
}

// ---------------------------------------------------------------------------
// Generic node GEMM: out[n][f] = maybe_silu( (in[n][:] * scale) @ W + b )
// One thread per node, 128 fp32 accumulators in registers, weights via
// uniform-address loads (scalarized to s_load by the compiler).
// ---------------------------------------------------------------------------
template <bool DIV_CNT, bool SILU>
__global__ __launch_bounds__(256) void node_gemm(
    const float* __restrict__ in, const float* __restrict__ w,
    const float* __restrict__ b, const float* __restrict__ cnt,
    float* __restrict__ out, int n) {
    int i = blockIdx.x * 256 + threadIdx.x;
    if (i >= n) return;

    float scale = 1.0f;
    if (DIV_CNT) {
        float c = cnt[i];
        scale = 1.0f / fmaxf(c, 1.0f);
    }

    float acc[HIDDEN];
#pragma unroll
    for (int f = 0; f < HIDDEN; ++f) acc[f] = (b != nullptr) ? b[f] : 0.0f;

    const float4* inp = (const float4*)(in + (size_t)i * HIDDEN);
    for (int k4 = 0; k4 < HIDDEN / 4; ++k4) {
        float4 v = inp[k4];
        v.x *= scale; v.y *= scale; v.z *= scale; v.w *= scale;
        const float* wr0 = w + (k4 * 4 + 0) * HIDDEN;
        const float* wr1 = w + (k4 * 4 + 1) * HIDDEN;
        const float* wr2 = w + (k4 * 4 + 2) * HIDDEN;
        const float* wr3 = w + (k4 * 4 + 3) * HIDDEN;
#pragma unroll
        for (int f = 0; f < HIDDEN; ++f) {
            acc[f] += v.x * wr0[f];
            acc[f] += v.y * wr1[f];
            acc[f] += v.z * wr2[f];
            acc[f] += v.w * wr3[f];
        }
    }

    float4* op = (float4*)(out + (size_t)i * HIDDEN);
#pragma unroll
    for (int f4 = 0; f4 < HIDDEN / 4; ++f4) {
        float4 r;
        float a0 = acc[4 * f4 + 0], a1 = acc[4 * f4 + 1];
        float a2 = acc[4 * f4 + 2], a3 = acc[4 * f4 + 3];
        if (SILU) {
            a0 = a0 / (1.0f + __expf(-a0));
            a1 = a1 / (1.0f + __expf(-a1));
            a2 = a2 / (1.0f + __expf(-a2));
            a3 = a3 / (1.0f + __expf(-a3));
        }
        r.x = a0; r.y = a1; r.z = a2; r.w = a3;
        op[f4] = r;
    }
}

// ---------------------------------------------------------------------------
// Edge kernel: one thread per edge.
//   h  = silu(attr @ w1 + b1)            (64 -> 128)
//   W  = (h @ w2 + b2) * C               (128 -> 128)
//   atomicAdd(agg[dst], xf[src] * W); atomicAdd(cnt[dst], 1)
// attr kept in 64 registers; 128 accumulator registers; weights uniform.
// ---------------------------------------------------------------------------
__global__ __launch_bounds__(256, 2) void edge_kernel(
    const int* __restrict__ src, const int* __restrict__ dst,
    const float* __restrict__ ew, const float* __restrict__ attr,
    const float* __restrict__ w1t, const float* __restrict__ b1,
    const float* __restrict__ w2, const float* __restrict__ b2,
    const float* __restrict__ xf, float* __restrict__ agg,
    float* __restrict__ cnt, int E) {
    int e = blockIdx.x * 256 + threadIdx.x;
    if (e >= E) return;

    float w = ew[e];
    float C = 0.5f * (__cosf(w * 0.62831853071795865f) + 1.0f);
    if (w >= 5.0f) C = 0.0f;

    float a[NRBF];
    const float4* ap = (const float4*)(attr + (size_t)e * NRBF);
#pragma unroll
    for (int i = 0; i < NRBF / 4; ++i) {
        float4 v = ap[i];
        a[4 * i + 0] = v.x; a[4 * i + 1] = v.y;
        a[4 * i + 2] = v.z; a[4 * i + 3] = v.w;
    }

    float acc[HIDDEN];
#pragma unroll
    for (int f = 0; f < HIDDEN; ++f) acc[f] = 0.0f;

    for (int k = 0; k < HIDDEN; ++k) {
        const float* wr = w1t + k * NRBF;
        float h0 = 0.f, h1 = 0.f, h2 = 0.f, h3 = 0.f;
#pragma unroll
        for (int r = 0; r < NRBF; r += 4) {
            h0 += a[r + 0] * wr[r + 0];
            h1 += a[r + 1] * wr[r + 1];
            h2 += a[r + 2] * wr[r + 2];
            h3 += a[r + 3] * wr[r + 3];
        }
        float h = b1[k] + ((h0 + h1) + (h2 + h3));
        h = h / (1.0f + __expf(-h));  // silu
        const float* w2r = w2 + k * HIDDEN;
#pragma unroll
        for (int f = 0; f < HIDDEN; ++f) acc[f] += h * w2r[f];
    }

    int s = src[e], d = dst[e];
    const float4* xr = (const float4*)(xf + (size_t)s * HIDDEN);
    float* ar = agg + (size_t)d * HIDDEN;
#pragma unroll
    for (int f4 = 0; f4 < HIDDEN / 4; ++f4) {
        float4 xv = xr[f4];
        float t0 = (acc[4 * f4 + 0] + b2[4 * f4 + 0]) * C;
        float t1 = (acc[4 * f4 + 1] + b2[4 * f4 + 1]) * C;
        float t2 = (acc[4 * f4 + 2] + b2[4 * f4 + 2]) * C;
        float t3 = (acc[4 * f4 + 3] + b2[4 * f4 + 3]) * C;
        atomicAdd(ar + 4 * f4 + 0, xv.x * t0);
        atomicAdd(ar + 4 * f4 + 1, xv.y * t1);
        atomicAdd(ar + 4 * f4 + 2, xv.z * t2);
        atomicAdd(ar + 4 * f4 + 3, xv.w * t3);
    }
    atomicAdd(cnt + d, 1.0f);
}

// ---------------------------------------------------------------------------
extern "C" void kernel_launch(void* const* d_in, const int* in_sizes, int n_in,
                              void* d_out, int out_size, void* d_ws, size_t ws_size,
                              hipStream_t stream) {
    const float* x   = (const float*)d_in[0];
    const int*   ei  = (const int*)d_in[1];    // int32 per harness contract
    const float* ew  = (const float*)d_in[2];
    const float* ea  = (const float*)d_in[3];
    const float* w1  = (const float*)d_in[4];
    const float* b1  = (const float*)d_in[5];
    const float* w2  = (const float*)d_in[6];
    const float* b2  = (const float*)d_in[7];
    const float* l1w = (const float*)d_in[8];
    const float* l2w = (const float*)d_in[9];
    const float* l2b = (const float*)d_in[10];
    const float* lw  = (const float*)d_in[11];
    const float* lb  = (const float*)d_in[12];

    const int N = in_sizes[0] / HIDDEN;   // 100000
    const int E = in_sizes[2];            // 1600000
    const int* src = ei;
    const int* dst = ei + E;

    // workspace layout (floats): agg[N*128] | cnt[N] | xf[N*128] | w1t[128*64]
    float* ws  = (float*)d_ws;
    float* agg = ws;
    float* cnt = agg + (size_t)N * HIDDEN;
    float* xf  = cnt + N;
    float* w1t = xf + (size_t)N * HIDDEN;

    // zero agg + cnt (contiguous)
    hipMemsetAsync(agg, 0, (size_t)(N * HIDDEN + N) * sizeof(float), stream);

    transpose_w1<<<(NRBF * HIDDEN + 255) / 256, 256, 0, stream>>>(w1, w1t);

    // xf = x @ lin1_w   (no bias)
    node_gemm<false, false><<<(N + 255) / 256, 256, 0, stream>>>(
        x, l1w, nullptr, nullptr, xf, N);

    // edge filter + gather*W + scatter-add
    edge_kernel<<<(E + 255) / 256, 256, 0, stream>>>(
        src, dst, ew, ea, w1t, b1, w2, b2, xf, agg, cnt, E);

    // tmp = silu(agg/cnt @ lin2_w + lin2_b)  (reuse xf buffer as tmp)
    node_gemm<true, true><<<(N + 255) / 256, 256, 0, stream>>>(
        agg, l2w, l2b, cnt, xf, N);

    // out = tmp @ lin_w + lin_b
    node_gemm<false, false><<<(N + 255) / 256, 256, 0, stream>>>(
        xf, lw, lb, nullptr, (float*)d_out, N);
}

// Round 2
// 4485.308 us; speedup vs baseline: 2.7100x; 2.7100x over previous
//
#include <hip/hip_runtime.h>
#include <hip/hip_bf16.h>

#define HIDDEN 128
#define NRBF 64

static __device__ __forceinline__ float silu(float v) {
    return v / (1.0f + __expf(-v));
}

// ---------------------------------------------------------------------------
// w1t[f][r] = w1[r][f]  (64x128 -> 128x64): edge kernel reads w1 rows
// contiguously with uniform (scalar) addresses.
// ---------------------------------------------------------------------------
__global__ void transpose_w1(const float* __restrict__ w1, float* __restrict__ w1t) {
    int idx = blockIdx.x * 256 + threadIdx.x;
    if (idx < NRBF * HIDDEN) {
        int r = idx >> 7;
        int f = idx & 127;
        w1t[f * NRBF + r] = w1[idx];
    }
}

// ---------------------------------------------------------------------------
// xf = x @ lin1_w  (no bias). One thread per node, 128 fp32 accumulators.
// ---------------------------------------------------------------------------
__global__ __launch_bounds__(256) void node_gemm(
    const float* __restrict__ in, const float* __restrict__ w,
    float* __restrict__ out, int n) {
    int i = blockIdx.x * 256 + threadIdx.x;
    if (i >= n) return;

    float acc[HIDDEN];
#pragma unroll
    for (int f = 0; f < HIDDEN; ++f) acc[f] = 0.0f;

    const float4* inp = (const float4*)(in + (size_t)i * HIDDEN);
    for (int k4 = 0; k4 < HIDDEN / 4; ++k4) {
        float4 v = inp[k4];
        const float* wr0 = w + (k4 * 4 + 0) * HIDDEN;
        const float* wr1 = w + (k4 * 4 + 1) * HIDDEN;
        const float* wr2 = w + (k4 * 4 + 2) * HIDDEN;
        const float* wr3 = w + (k4 * 4 + 3) * HIDDEN;
#pragma unroll
        for (int f = 0; f < HIDDEN; ++f) {
            acc[f] += v.x * wr0[f];
            acc[f] += v.y * wr1[f];
            acc[f] += v.z * wr2[f];
            acc[f] += v.w * wr3[f];
        }
    }

    float4* op = (float4*)(out + (size_t)i * HIDDEN);
#pragma unroll
    for (int f4 = 0; f4 < HIDDEN / 4; ++f4) {
        float4 r;
        r.x = acc[4 * f4 + 0]; r.y = acc[4 * f4 + 1];
        r.z = acc[4 * f4 + 2]; r.w = acc[4 * f4 + 3];
        op[f4] = r;
    }
}

// ---------------------------------------------------------------------------
// CSR build: histogram of dst, exclusive scan, ticket fill.
// ---------------------------------------------------------------------------
__global__ void hist_kernel(const int* __restrict__ dst, int* __restrict__ counts, int E) {
    int e = blockIdx.x * 256 + threadIdx.x;
    if (e < E) atomicAdd(&counts[dst[e]], 1);
}

__global__ __launch_bounds__(1024) void scan_kernel(
    const int* __restrict__ counts, int* __restrict__ off,
    int* __restrict__ cursor, int n) {
    __shared__ int sdata[1024];
    __shared__ int running;
    if (threadIdx.x == 0) running = 0;
    __syncthreads();
    for (int base = 0; base < n; base += 1024) {
        int i = base + threadIdx.x;
        int v = (i < n) ? counts[i] : 0;
        sdata[threadIdx.x] = v;
        __syncthreads();
        for (int s = 1; s < 1024; s <<= 1) {
            int t = (threadIdx.x >= s) ? sdata[threadIdx.x - s] : 0;
            __syncthreads();
            sdata[threadIdx.x] += t;
            __syncthreads();
        }
        int excl = sdata[threadIdx.x] - v;
        if (i < n) {
            int o = running + excl;
            off[i] = o;
            cursor[i] = o;
        }
        __syncthreads();
        if (threadIdx.x == 1023) running += sdata[1023];
        __syncthreads();
    }
    if (threadIdx.x == 0) off[n] = running;
}

__global__ void fill_kernel(const int* __restrict__ dst, int* __restrict__ cursor,
                            int* __restrict__ csr, int E) {
    int e = blockIdx.x * 256 + threadIdx.x;
    if (e < E) {
        int pos = atomicAdd(&cursor[dst[e]], 1);
        csr[pos] = e;
    }
}

// ---------------------------------------------------------------------------
// Phase A: per-edge filter MLP, then msg[e] = xf[src]*W*C  (bf16, no atomics)
// ---------------------------------------------------------------------------
__global__ __launch_bounds__(256, 2) void msg_kernel(
    const int* __restrict__ src, const float* __restrict__ ew,
    const float* __restrict__ attr, const float* __restrict__ w1t,
    const float* __restrict__ b1, const float* __restrict__ w2,
    const float* __restrict__ b2, const float* __restrict__ xf,
    __hip_bfloat16* __restrict__ msg, int E) {
    int e = blockIdx.x * 256 + threadIdx.x;
    if (e >= E) return;

    float w = ew[e];
    float C = 0.5f * (__cosf(w * 0.62831853071795865f) + 1.0f);
    if (w >= 5.0f) C = 0.0f;

    float a[NRBF];
    const float4* ap = (const float4*)(attr + (size_t)e * NRBF);
#pragma unroll
    for (int i = 0; i < NRBF / 4; ++i) {
        float4 v = ap[i];
        a[4 * i + 0] = v.x; a[4 * i + 1] = v.y;
        a[4 * i + 2] = v.z; a[4 * i + 3] = v.w;
    }

    float acc[HIDDEN];
#pragma unroll
    for (int f = 0; f < HIDDEN; ++f) acc[f] = 0.0f;

    for (int k = 0; k < HIDDEN; ++k) {
        const float* wr = w1t + k * NRBF;
        float h0 = 0.f, h1 = 0.f, h2 = 0.f, h3 = 0.f;
#pragma unroll
        for (int r = 0; r < NRBF; r += 4) {
            h0 += a[r + 0] * wr[r + 0];
            h1 += a[r + 1] * wr[r + 1];
            h2 += a[r + 2] * wr[r + 2];
            h3 += a[r + 3] * wr[r + 3];
        }
        float h = silu(b1[k] + ((h0 + h1) + (h2 + h3)));
        const float* w2r = w2 + k * HIDDEN;
#pragma unroll
        for (int f = 0; f < HIDDEN; ++f) acc[f] += h * w2r[f];
    }

    int s = src[e];
    const float4* xr = (const float4*)(xf + (size_t)s * HIDDEN);
    uint4* mr = (uint4*)(msg + (size_t)e * HIDDEN);  // 8 bf16 per uint4
#pragma unroll
    for (int f8 = 0; f8 < HIDDEN / 8; ++f8) {
        float4 x0 = xr[2 * f8 + 0];
        float4 x1 = xr[2 * f8 + 1];
        float t[8];
        t[0] = x0.x * (acc[8 * f8 + 0] + b2[8 * f8 + 0]) * C;
        t[1] = x0.y * (acc[8 * f8 + 1] + b2[8 * f8 + 1]) * C;
        t[2] = x0.z * (acc[8 * f8 + 2] + b2[8 * f8 + 2]) * C;
        t[3] = x0.w * (acc[8 * f8 + 3] + b2[8 * f8 + 3]) * C;
        t[4] = x1.x * (acc[8 * f8 + 4] + b2[8 * f8 + 4]) * C;
        t[5] = x1.y * (acc[8 * f8 + 5] + b2[8 * f8 + 5]) * C;
        t[6] = x1.z * (acc[8 * f8 + 6] + b2[8 * f8 + 6]) * C;
        t[7] = x1.w * (acc[8 * f8 + 7] + b2[8 * f8 + 7]) * C;
        union { unsigned short us[8]; uint4 v; } pk;
#pragma unroll
        for (int j = 0; j < 8; ++j) {
            __hip_bfloat16 b = __float2bfloat16(t[j]);
            pk.us[j] = *reinterpret_cast<unsigned short*>(&b);
        }
        mr[f8] = pk.v;
    }
}

// ---------------------------------------------------------------------------
// Phase B: per-node gather (CSR) -> mean -> lin2 -> silu -> lin  (fused tail)
// One 128-thread block per node; LDS row broadcast for the two GEMVs.
// ---------------------------------------------------------------------------
__global__ __launch_bounds__(128) void gather_tail(
    const int* __restrict__ off, const int* __restrict__ csr,
    const __hip_bfloat16* __restrict__ msg,
    const float* __restrict__ l2w, const float* __restrict__ l2b,
    const float* __restrict__ lw, const float* __restrict__ lb,
    float* __restrict__ out, int n) {
    int node = blockIdx.x;
    int f = threadIdx.x;
    int s = off[node], e = off[node + 1];

    float acc = 0.0f;
    for (int j = s; j < e; ++j) {
        int eid = csr[j];
        acc += __bfloat162float(msg[(size_t)eid * HIDDEN + f]);
    }
    float deg = (float)(e - s);
    acc = acc / fmaxf(deg, 1.0f);

    __shared__ float row[HIDDEN];
    row[f] = acc;
    __syncthreads();

    float a2 = l2b[f];
#pragma unroll
    for (int k4 = 0; k4 < HIDDEN / 4; ++k4) {
        float4 r = ((const float4*)row)[k4];   // LDS broadcast (same addr all lanes)
        const float* wr = l2w + k4 * 4 * HIDDEN;
        a2 += r.x * wr[f] + r.y * wr[HIDDEN + f] + r.z * wr[2 * HIDDEN + f] + r.w * wr[3 * HIDDEN + f];
    }
    a2 = silu(a2);
    __syncthreads();
    row[f] = a2;
    __syncthreads();

    float a3 = lb[f];
#pragma unroll
    for (int k4 = 0; k4 < HIDDEN / 4; ++k4) {
        float4 r = ((const float4*)row)[k4];
        const float* wr = lw + k4 * 4 * HIDDEN;
        a3 += r.x * wr[f] + r.y * wr[HIDDEN + f] + r.z * wr[2 * HIDDEN + f] + r.w * wr[3 * HIDDEN + f];
    }
    out[(size_t)node * HIDDEN + f] = a3;
}

// ---------------------------------------------------------------------------
static inline char* align_up(char* p, size_t a) {
    return (char*)(((uintptr_t)p + a - 1) & ~(uintptr_t)(a - 1));
}

extern "C" void kernel_launch(void* const* d_in, const int* in_sizes, int n_in,
                              void* d_out, int out_size, void* d_ws, size_t ws_size,
                              hipStream_t stream) {
    const float* x   = (const float*)d_in[0];
    const int*   ei  = (const int*)d_in[1];
    const float* ew  = (const float*)d_in[2];
    const float* ea  = (const float*)d_in[3];
    const float* w1  = (const float*)d_in[4];
    const float* b1  = (const float*)d_in[5];
    const float* w2  = (const float*)d_in[6];
    const float* b2  = (const float*)d_in[7];
    const float* l1w = (const float*)d_in[8];
    const float* l2w = (const float*)d_in[9];
    const float* l2b = (const float*)d_in[10];
    const float* lw  = (const float*)d_in[11];
    const float* lb  = (const float*)d_in[12];

    const int N = in_sizes[0] / HIDDEN;   // 100000
    const int E = in_sizes[2];            // 1600000
    const int* src = ei;
    const int* dst = ei + E;

    // workspace carve-up (256B aligned)
    char* p = (char*)d_ws;
    float* xf = (float*)p;                 p = align_up(p + (size_t)N * HIDDEN * 4, 256);
    float* w1t = (float*)p;                p = align_up(p + NRBF * HIDDEN * 4, 256);
    int* counts = (int*)p;                 p = align_up(p + (size_t)N * 4, 256);
    int* off = (int*)p;                    p = align_up(p + (size_t)(N + 1) * 4, 256);
    int* cursor = (int*)p;                 p = align_up(p + (size_t)N * 4, 256);
    int* csr = (int*)p;                    p = align_up(p + (size_t)E * 4, 256);
    __hip_bfloat16* msg = (__hip_bfloat16*)p;  // E*128 bf16 = 410 MB

    hipMemsetAsync(counts, 0, (size_t)N * sizeof(int), stream);

    transpose_w1<<<(NRBF * HIDDEN + 255) / 256, 256, 0, stream>>>(w1, w1t);

    node_gemm<<<(N + 255) / 256, 256, 0, stream>>>(x, l1w, xf, N);

    hist_kernel<<<(E + 255) / 256, 256, 0, stream>>>(dst, counts, E);
    scan_kernel<<<1, 1024, 0, stream>>>(counts, off, cursor, N);
    fill_kernel<<<(E + 255) / 256, 256, 0, stream>>>(dst, cursor, csr, E);

    msg_kernel<<<(E + 255) / 256, 256, 0, stream>>>(
        src, ew, ea, w1t, b1, w2, b2, xf, msg, E);

    gather_tail<<<N, 128, 0, stream>>>(
        off, csr, msg, l2w, l2b, lw, lb, (float*)d_out, N);
}

// Round 3
// 2435.290 us; speedup vs baseline: 4.9913x; 1.8418x over previous
//
#include <hip/hip_runtime.h>
#include <hip/hip_bf16.h>

#define HIDDEN 128
#define NRBF 64

typedef __attribute__((ext_vector_type(8))) short short8;   // 8 bf16 (4 VGPRs)
typedef __attribute__((ext_vector_type(4))) float float4v;  // 4 fp32 acc

#define ATTR_LD 72   // bf16 stride for attr tile (64+8): 16B-aligned rows
#define H_LD 136     // bf16 stride for H tile (128+8): 16B-aligned rows

static __device__ __forceinline__ float silu(float v) {
    return v / (1.0f + __expf(-v));
}

static __device__ __forceinline__ short f2bf(float v) {
    __hip_bfloat16 b = __float2bfloat16(v);
    return *reinterpret_cast<short*>(&b);
}

// ---------------------------------------------------------------------------
// Weights -> bf16, transposed to [n][k] so MFMA B-fragments are contiguous.
// ---------------------------------------------------------------------------
__global__ __launch_bounds__(256) void conv_weights(
    const float* __restrict__ w1, const float* __restrict__ w2,
    short* __restrict__ w1f, short* __restrict__ w2f) {
    int idx = blockIdx.x * 256 + threadIdx.x;
    if (idx < HIDDEN * NRBF) {           // w1f[n][k] = w1[k][n], 128x64
        int n = idx >> 6, k = idx & 63;
        w1f[idx] = f2bf(w1[k * HIDDEN + n]);
    }
    if (idx < HIDDEN * HIDDEN) {         // w2f[n][k] = w2[k][n], 128x128
        int n = idx >> 7, k = idx & 127;
        w2f[idx] = f2bf(w2[k * HIDDEN + n]);
    }
}

// ---------------------------------------------------------------------------
// xf = x @ lin1_w  (fp32, one thread per node)
// ---------------------------------------------------------------------------
__global__ __launch_bounds__(256) void node_gemm(
    const float* __restrict__ in, const float* __restrict__ w,
    float* __restrict__ out, int n) {
    int i = blockIdx.x * 256 + threadIdx.x;
    if (i >= n) return;

    float acc[HIDDEN];
#pragma unroll
    for (int f = 0; f < HIDDEN; ++f) acc[f] = 0.0f;

    const float4* inp = (const float4*)(in + (size_t)i * HIDDEN);
    for (int k4 = 0; k4 < HIDDEN / 4; ++k4) {
        float4 v = inp[k4];
        const float* wr0 = w + (k4 * 4 + 0) * HIDDEN;
        const float* wr1 = w + (k4 * 4 + 1) * HIDDEN;
        const float* wr2 = w + (k4 * 4 + 2) * HIDDEN;
        const float* wr3 = w + (k4 * 4 + 3) * HIDDEN;
#pragma unroll
        for (int f = 0; f < HIDDEN; ++f) {
            acc[f] += v.x * wr0[f];
            acc[f] += v.y * wr1[f];
            acc[f] += v.z * wr2[f];
            acc[f] += v.w * wr3[f];
        }
    }

    float4* op = (float4*)(out + (size_t)i * HIDDEN);
#pragma unroll
    for (int f4 = 0; f4 < HIDDEN / 4; ++f4) {
        float4 r;
        r.x = acc[4 * f4 + 0]; r.y = acc[4 * f4 + 1];
        r.z = acc[4 * f4 + 2]; r.w = acc[4 * f4 + 3];
        op[f4] = r;
    }
}

// ---------------------------------------------------------------------------
// CSR build: histogram, hierarchical scan (3 small kernels), ticket fill.
// ---------------------------------------------------------------------------
__global__ void hist_kernel(const int* __restrict__ dst, int* __restrict__ counts, int E) {
    int e = blockIdx.x * 256 + threadIdx.x;
    if (e < E) atomicAdd(&counts[dst[e]], 1);
}

__global__ __launch_bounds__(256) void scan_part1(
    const int* __restrict__ counts, int* __restrict__ bsums, int n) {
    int base = blockIdx.x * 1024;
    int t = threadIdx.x;
    int s = 0;
#pragma unroll
    for (int j = 0; j < 4; ++j) {
        int i = base + t * 4 + j;
        if (i < n) s += counts[i];
    }
    for (int off = 32; off; off >>= 1) s += __shfl_down(s, off, 64);
    __shared__ int wsum[4];
    if ((t & 63) == 0) wsum[t >> 6] = s;
    __syncthreads();
    if (t == 0) bsums[blockIdx.x] = wsum[0] + wsum[1] + wsum[2] + wsum[3];
}

__global__ __launch_bounds__(1024) void scan_part2(
    int* __restrict__ bsums, int nb, int* __restrict__ off_total) {
    __shared__ int sd[1024];
    int t = threadIdx.x;
    int v = (t < nb) ? bsums[t] : 0;
    sd[t] = v;
    __syncthreads();
    for (int s = 1; s < 1024; s <<= 1) {
        int u = (t >= s) ? sd[t - s] : 0;
        __syncthreads();
        sd[t] += u;
        __syncthreads();
    }
    if (t < nb) bsums[t] = sd[t] - v;  // exclusive
    if (t == 1023) *off_total = sd[1023];
}

__global__ __launch_bounds__(256) void scan_part3(
    const int* __restrict__ counts, const int* __restrict__ bsums,
    int* __restrict__ off, int* __restrict__ cursor, int n) {
    int base = blockIdx.x * 1024;
    int t = threadIdx.x;
    int i0 = base + t * 4;
    int v[4];
#pragma unroll
    for (int j = 0; j < 4; ++j) v[j] = (i0 + j < n) ? counts[i0 + j] : 0;
    int tsum = v[0] + v[1] + v[2] + v[3];
    int incl = tsum;
    for (int d = 1; d < 64; d <<= 1) {
        int u = __shfl_up(incl, d, 64);
        if ((t & 63) >= d) incl += u;
    }
    __shared__ int wtot[4];
    if ((t & 63) == 63) wtot[t >> 6] = incl;
    __syncthreads();
    int woff = 0;
    for (int w = 0; w < (t >> 6); ++w) woff += wtot[w];
    int run = bsums[blockIdx.x] + woff + (incl - tsum);
#pragma unroll
    for (int j = 0; j < 4; ++j) {
        if (i0 + j < n) {
            off[i0 + j] = run;
            cursor[i0 + j] = run;
            run += v[j];
        }
    }
}

__global__ void fill_kernel(const int* __restrict__ dst, int* __restrict__ cursor,
                            int* __restrict__ csr, int E) {
    int e = blockIdx.x * 256 + threadIdx.x;
    if (e < E) {
        int pos = atomicAdd(&cursor[dst[e]], 1);
        csr[pos] = e;
    }
}

// ---------------------------------------------------------------------------
// Fused MFMA msg kernel. One 256-thread block (4 waves) per 128 CSR positions.
//   GEMM1: H = silu(attr @ w1 + b1)   [128x64]@[64x128], K-steps=2
//   GEMM2: W = H @ w2 + b2            [128x128]@[128x128], K-steps=4
//   msg[p][f] = bf16( xf[src][f] * W * C )   (contiguous in CSR order)
// Wave w owns filter columns [32w, 32w+32). MFMA 16x16x32_bf16:
//   A-frag: A[m=lane&15][k=quad*8+j]; B-frag: B[k=quad*8+j][n=lane&15]
//   C/D:    D[row=quad*4+reg][col=lane&15]
// ---------------------------------------------------------------------------
__global__ __launch_bounds__(256, 3) void msg_mfma(
    const int* __restrict__ csr, const int* __restrict__ src,
    const float* __restrict__ ew, const float* __restrict__ attr,
    const short* __restrict__ w1f, const float* __restrict__ b1,
    const short* __restrict__ w2f, const float* __restrict__ b2,
    const float* __restrict__ xf, __hip_bfloat16* __restrict__ msg, int E) {
    __shared__ short attr_s[128 * ATTR_LD];
    __shared__ short h_s[128 * H_LD];
    __shared__ int srcs[128];
    __shared__ float Cc[128];

    const int p0 = blockIdx.x * 128;
    const int tid = threadIdx.x;
    const int wave = tid >> 6;
    const int lane = tid & 63;
    const int quad = lane >> 4;
    const int lc = lane & 15;
    const int nbase = wave * 32;

    // ---- stage: per-edge metadata + attr rows (fp32 -> bf16) ----
    {
        int row = tid >> 1;
        int half = tid & 1;
        int p = p0 + row;
        int eid = (p < E) ? csr[p] : 0;
        if (half == 0) {
            srcs[row] = src[eid];
            float w = ew[eid];
            float C = 0.5f * (__cosf(w * 0.62831853071795865f) + 1.0f);
            if (w >= 5.0f) C = 0.0f;
            Cc[row] = C;
        }
        const float4* ap = (const float4*)(attr + (size_t)eid * NRBF + half * 32);
        short* dp = attr_s + row * ATTR_LD + half * 32;
#pragma unroll
        for (int i = 0; i < 8; ++i) {
            float4 v = ap[i];
            short4 s4;
            s4.x = f2bf(v.x); s4.y = f2bf(v.y); s4.z = f2bf(v.z); s4.w = f2bf(v.w);
            *(short4*)(dp + i * 4) = s4;
        }
    }
    __syncthreads();

    // ---- GEMM1: H = attr @ w1 ----
    float4v acc[8][2];
#pragma unroll
    for (int mt = 0; mt < 8; ++mt)
#pragma unroll
        for (int nt = 0; nt < 2; ++nt) acc[mt][nt] = (float4v){0.f, 0.f, 0.f, 0.f};

    short8 bf1[2][2];  // [kk][nt]
#pragma unroll
    for (int kk = 0; kk < 2; ++kk)
#pragma unroll
        for (int nt = 0; nt < 2; ++nt)
            bf1[kk][nt] = *(const short8*)(w1f + (nbase + nt * 16 + lc) * NRBF + kk * 32 + quad * 8);

#pragma unroll
    for (int kk = 0; kk < 2; ++kk) {
#pragma unroll
        for (int mt = 0; mt < 8; ++mt) {
            short8 af = *(const short8*)(attr_s + (mt * 16 + lc) * ATTR_LD + kk * 32 + quad * 8);
            acc[mt][0] = __builtin_amdgcn_mfma_f32_16x16x32_bf16(af, bf1[kk][0], acc[mt][0], 0, 0, 0);
            acc[mt][1] = __builtin_amdgcn_mfma_f32_16x16x32_bf16(af, bf1[kk][1], acc[mt][1], 0, 0, 0);
        }
    }

    // ---- bias + silu -> h_s (bf16, A-fragment-friendly [edge][k]) ----
#pragma unroll
    for (int nt = 0; nt < 2; ++nt) {
        int col = nbase + nt * 16 + lc;
        float bb = b1[col];
#pragma unroll
        for (int mt = 0; mt < 8; ++mt) {
            float4v a = acc[mt][nt];
#pragma unroll
            for (int r = 0; r < 4; ++r) {
                int row = mt * 16 + quad * 4 + r;
                h_s[row * H_LD + col] = f2bf(silu(a[r] + bb));
            }
        }
    }
    __syncthreads();

    // ---- GEMM2: W = H @ w2 ----
    float4v acc2[8][2];
#pragma unroll
    for (int mt = 0; mt < 8; ++mt)
#pragma unroll
        for (int nt = 0; nt < 2; ++nt) acc2[mt][nt] = (float4v){0.f, 0.f, 0.f, 0.f};

#pragma unroll
    for (int kk = 0; kk < 4; ++kk) {
        short8 bb0 = *(const short8*)(w2f + (nbase + 0 * 16 + lc) * HIDDEN + kk * 32 + quad * 8);
        short8 bb1 = *(const short8*)(w2f + (nbase + 1 * 16 + lc) * HIDDEN + kk * 32 + quad * 8);
#pragma unroll
        for (int mt = 0; mt < 8; ++mt) {
            short8 af = *(const short8*)(h_s + (mt * 16 + lc) * H_LD + kk * 32 + quad * 8);
            acc2[mt][0] = __builtin_amdgcn_mfma_f32_16x16x32_bf16(af, bb0, acc2[mt][0], 0, 0, 0);
            acc2[mt][1] = __builtin_amdgcn_mfma_f32_16x16x32_bf16(af, bb1, acc2[mt][1], 0, 0, 0);
        }
    }

    // ---- epilogue: * C, * xf[src], write bf16 msg in CSR order ----
#pragma unroll
    for (int nt = 0; nt < 2; ++nt) {
        int f = nbase + nt * 16 + lc;
        float bb = b2[f];
#pragma unroll
        for (int mt = 0; mt < 8; ++mt) {
            float4v a = acc2[mt][nt];
#pragma unroll
            for (int r = 0; r < 4; ++r) {
                int row = mt * 16 + quad * 4 + r;
                int p = p0 + row;
                if (p < E) {
                    float Wv = (a[r] + bb) * Cc[row];
                    float xv = xf[(size_t)srcs[row] * HIDDEN + f];
                    msg[(size_t)p * HIDDEN + f] = __float2bfloat16(xv * Wv);
                }
            }
        }
    }
}

// ---------------------------------------------------------------------------
// Phase B: per-node contiguous msg mean -> lin2 -> silu -> lin (fused tail)
// ---------------------------------------------------------------------------
__global__ __launch_bounds__(128) void gather_tail(
    const int* __restrict__ off, const __hip_bfloat16* __restrict__ msg,
    const float* __restrict__ l2w, const float* __restrict__ l2b,
    const float* __restrict__ lw, const float* __restrict__ lb,
    float* __restrict__ out, int n) {
    int node = blockIdx.x;
    int f = threadIdx.x;
    int s = off[node], e = off[node + 1];

    float acc = 0.0f;
    for (int j = s; j < e; ++j)
        acc += __bfloat162float(msg[(size_t)j * HIDDEN + f]);
    float deg = (float)(e - s);
    acc = acc / fmaxf(deg, 1.0f);

    __shared__ float row[HIDDEN];
    row[f] = acc;
    __syncthreads();

    float a2 = l2b[f];
#pragma unroll
    for (int k4 = 0; k4 < HIDDEN / 4; ++k4) {
        float4 r = ((const float4*)row)[k4];
        const float* wr = l2w + k4 * 4 * HIDDEN;
        a2 += r.x * wr[f] + r.y * wr[HIDDEN + f] + r.z * wr[2 * HIDDEN + f] + r.w * wr[3 * HIDDEN + f];
    }
    a2 = silu(a2);
    __syncthreads();
    row[f] = a2;
    __syncthreads();

    float a3 = lb[f];
#pragma unroll
    for (int k4 = 0; k4 < HIDDEN / 4; ++k4) {
        float4 r = ((const float4*)row)[k4];
        const float* wr = lw + k4 * 4 * HIDDEN;
        a3 += r.x * wr[f] + r.y * wr[HIDDEN + f] + r.z * wr[2 * HIDDEN + f] + r.w * wr[3 * HIDDEN + f];
    }
    out[(size_t)node * HIDDEN + f] = a3;
}

// ---------------------------------------------------------------------------
static inline char* align_up(char* p, size_t a) {
    return (char*)(((uintptr_t)p + a - 1) & ~(uintptr_t)(a - 1));
}

extern "C" void kernel_launch(void* const* d_in, const int* in_sizes, int n_in,
                              void* d_out, int out_size, void* d_ws, size_t ws_size,
                              hipStream_t stream) {
    const float* x   = (const float*)d_in[0];
    const int*   ei  = (const int*)d_in[1];
    const float* ew  = (const float*)d_in[2];
    const float* ea  = (const float*)d_in[3];
    const float* w1  = (const float*)d_in[4];
    const float* b1  = (const float*)d_in[5];
    const float* w2  = (const float*)d_in[6];
    const float* b2  = (const float*)d_in[7];
    const float* l1w = (const float*)d_in[8];
    const float* l2w = (const float*)d_in[9];
    const float* l2b = (const float*)d_in[10];
    const float* lw  = (const float*)d_in[11];
    const float* lb  = (const float*)d_in[12];

    const int N = in_sizes[0] / HIDDEN;   // 100000
    const int E = in_sizes[2];            // 1600000
    const int* src = ei;
    const int* dst = ei + E;

    const int NB = (N + 1023) / 1024;     // scan blocks

    // workspace carve-up (256B aligned)
    char* p = (char*)d_ws;
    float* xf = (float*)p;        p = align_up(p + (size_t)N * HIDDEN * 4, 256);
    short* w1f = (short*)p;       p = align_up(p + HIDDEN * NRBF * 2, 256);
    short* w2f = (short*)p;       p = align_up(p + HIDDEN * HIDDEN * 2, 256);
    int* counts = (int*)p;        p = align_up(p + (size_t)N * 4, 256);
    int* off = (int*)p;           p = align_up(p + (size_t)(N + 1) * 4, 256);
    int* cursor = (int*)p;        p = align_up(p + (size_t)N * 4, 256);
    int* bsums = (int*)p;         p = align_up(p + (size_t)NB * 4, 256);
    int* csr = (int*)p;           p = align_up(p + (size_t)E * 4, 256);
    __hip_bfloat16* msg = (__hip_bfloat16*)p;  // E*128 bf16 = 410 MB

    hipMemsetAsync(counts, 0, (size_t)N * sizeof(int), stream);

    conv_weights<<<(HIDDEN * HIDDEN + 255) / 256, 256, 0, stream>>>(w1, w2, w1f, w2f);

    node_gemm<<<(N + 255) / 256, 256, 0, stream>>>(x, l1w, xf, N);

    hist_kernel<<<(E + 255) / 256, 256, 0, stream>>>(dst, counts, E);
    scan_part1<<<NB, 256, 0, stream>>>(counts, bsums, N);
    scan_part2<<<1, 1024, 0, stream>>>(bsums, NB, off + N);
    scan_part3<<<NB, 256, 0, stream>>>(counts, bsums, off, cursor, N);
    fill_kernel<<<(E + 255) / 256, 256, 0, stream>>>(dst, cursor, csr, E);

    msg_mfma<<<(E + 127) / 128, 256, 0, stream>>>(
        csr, src, ew, ea, w1f, b1, w2f, b2, xf, msg, E);

    gather_tail<<<N, 128, 0, stream>>>(
        off, msg, l2w, l2b, lw, lb, (float*)d_out, N);
}